// Round 10
// baseline (281.735 us; speedup 1.0000x reference)
//
#include <hip/hip_runtime.h>
#include <hip/hip_bf16.h>
#include <math.h>

typedef __hip_bfloat16 bf16;
typedef __attribute__((ext_vector_type(8))) short short8;
typedef __attribute__((ext_vector_type(4))) float f32x4;

#define N_NODES 50000
#define N_EDGES 800000
#define IN_DIM 50
#define HIDDEN 256
#define NCLS 121
#define PSTR 128     // padded stride for pb/qrb/qlb rows (bf16)
#define LDSPITCH 264 // proj2 LDS pitch (bf16)
#define NCHUNK 196   // ceil(50000/256) scan chunks
#define P2ROWS 64    // proj2 rows per block (B-fragment reuse x4)
#define FEDGE 1024   // LDS-staged csr indices per block (8 nodes, avg 128)

// ---- workspace layout (4-byte units) ----
// degi 0..50000 | off 50048.. | csr 150160..950160
// hb  bf16 50000x256 : [950272, 7350272)   -- ALSO aliased as rank[] (int, 800000)
// pb  bf16 50000x128 : [7350272, 10550272) -- ALSO aliased as xbp (bf16 50000x64)
// ab  bf16 50000x128 : [10550272, 13750272)
// qrb bf16 50000x128 : [15000272, 18200272)
// qlb bf16 50000x128 : [18200272, 21400272)
// bw  bf16 8*384*32  : [21400272, 21449424)
// bw1 bf16 4*512*32  : [21449424, 21482192)
// csum int [21482240,+196)
#define OFF_OFF   50048
#define OFF_CSR   150160
#define OFF_HB    950272
#define OFF_PB    7350272
#define OFF_AB    10550272
#define OFF_QRB   15000272
#define OFF_QLB   18200272
#define OFF_BW    21400272
#define OFF_BW1   21449424
#define OFF_CSUM  21482240

__device__ __forceinline__ int clampi(int v, int hi) {
    return v < 0 ? 0 : (v >= hi ? hi - 1 : v);
}

__device__ __forceinline__ float uf(unsigned u) { return __uint_as_float(u); }

// ---------------- prep: convx(+xbp) + packw1 + packw2 + degi zero -----------
__global__ __launch_bounds__(256) void prep_r27(
    const float* __restrict__ x, bf16* __restrict__ xbp, bf16* __restrict__ ab,
    const float* __restrict__ w1l, const float* __restrict__ w1r,
    const float* __restrict__ wl1, bf16* __restrict__ bw1,
    const float* __restrict__ w2l, const float* __restrict__ w2r,
    const float* __restrict__ wl2, bf16* __restrict__ bw,
    int* __restrict__ degi) {
    int b = blockIdx.x;
    if (b < 25000) {
        int i = b * 256 + threadIdx.x;  // < 6,400,000 exactly
        int n = i >> 7, c = i & 127;
        float v = 0.0f;
        if (c >= 64 && c < 64 + IN_DIM) v = x[n * IN_DIM + (c - 64)];
        ab[i] = __float2bfloat16(v);
        if (c < 64) {
            float xv = (c < IN_DIM) ? x[n * IN_DIM + c] : 0.0f;
            xbp[n * 64 + c] = __float2bfloat16(xv);
        }
    } else if (b < 25256) {
        int i = (b - 25000) * 256 + threadIdx.x;  // < 65536 exactly
        int kt = i / 16384, r = i % 16384, c = r / 32, t32 = r % 32;
        int q = t32 >> 3, j = t32 & 7;
        int k = kt * 32 + q * 8 + j;  // 0..127
        float v = 0.0f;
        if (k < 64) {
            if (k < IN_DIM && c < 256) v = w1l[k * HIDDEN + c];
        } else {
            int kr = k - 64;
            if (kr < IN_DIM)
                v = (c < 256) ? w1r[kr * HIDDEN + c] : wl1[kr * HIDDEN + (c - 256)];
        }
        bw1[i] = __float2bfloat16(v);
    } else if (b < 25640) {
        int i = (b - 25256) * 256 + threadIdx.x;  // < 98304 exactly
        int kt = i / 12288, r = i % 12288, c = r / 32, t32 = r % 32;
        int q = t32 >> 3, j = t32 & 7;
        int k = kt * 32 + q * 8 + j;
        int mat = c >> 7, cls = c & 127;
        float v = 0.0f;
        if (cls < NCLS) {
            const float* w = (mat == 0) ? w2l : ((mat == 1) ? w2r : wl2);
            v = w[k * NCLS + cls];
        }
        bw[i] = __float2bfloat16(v);
    } else {
        int i = (b - 25640) * 256 + threadIdx.x;
        if (i < N_NODES) degi[i] = 0;
    }
}

// ---------------- degrank: count degree AND record per-edge rank ------------
__global__ __launch_bounds__(256) void degrank_r27(const int* __restrict__ dst,
                                                   int* __restrict__ degi,
                                                   int* __restrict__ rank) {
    int e = blockIdx.x * 256 + threadIdx.x;
    if (e < N_EDGES) {
        int d = clampi(dst[e], N_NODES);
        rank[e] = atomicAdd(&degi[d], 1);
    }
}

// ---------------- scan phase 1: per-chunk sums ----------------
__global__ __launch_bounds__(256) void chunksum_r27(const int* __restrict__ degi,
                                                    int* __restrict__ csum) {
    __shared__ int red[256];
    int i = blockIdx.x * 256 + threadIdx.x;
    red[threadIdx.x] = (i < N_NODES) ? degi[i] : 0;
    __syncthreads();
    for (int s = 128; s > 0; s >>= 1) {
        if (threadIdx.x < s) red[threadIdx.x] += red[threadIdx.x + s];
        __syncthreads();
    }
    if (threadIdx.x == 0) csum[blockIdx.x] = red[0];
}

// ---------------- scan phase 2 (merged): chunk scan + per-chunk scatter -----
__global__ __launch_bounds__(256) void scanscatter_r27(const int* __restrict__ csum,
                                                       const int* __restrict__ degi,
                                                       int* __restrict__ off) {
    __shared__ int cs[256];
    __shared__ int s[256];
    int t = threadIdx.x;
    int cv = (t < NCHUNK) ? csum[t] : 0;
    cs[t] = cv;
    __syncthreads();
    for (int d = 1; d < 256; d <<= 1) {
        int u = (t >= d) ? cs[t - d] : 0;
        __syncthreads();
        cs[t] += u;
        __syncthreads();
    }
    int cb = cs[blockIdx.x] - csum[blockIdx.x];  // exclusive base of this chunk
    if (blockIdx.x == 0 && t == 0) off[N_NODES] = cs[NCHUNK - 1];
    int i = blockIdx.x * 256 + t;
    int dv = (i < N_NODES) ? degi[i] : 0;
    s[t] = dv;
    __syncthreads();
    for (int d = 1; d < 256; d <<= 1) {
        int u = (t >= d) ? s[t - d] : 0;
        __syncthreads();
        s[t] += u;
        __syncthreads();
    }
    if (i < N_NODES) off[i] = s[t] - dv + cb;
}

// ---------------- csrfill2: atomic-free scatter using precomputed ranks -----
__global__ __launch_bounds__(256) void csrfill2_r27(const int* __restrict__ src,
                                                    const int* __restrict__ dst,
                                                    const int* __restrict__ rank,
                                                    const int* __restrict__ off,
                                                    int* __restrict__ csr) {
    int e = blockIdx.x * 256 + threadIdx.x;
    if (e >= N_EDGES) return;
    int d = clampi(dst[e], N_NODES);
    csr[off[d] + rank[e]] = clampi(src[e], N_NODES);
}

// ---------------- gather1: mean-aggregate x, 4 loads in flight --------------
__global__ __launch_bounds__(256) void gather1_r27(
    const uint2* __restrict__ xb2, const int* __restrict__ off,
    const int* __restrict__ csr, const int* __restrict__ degi,
    unsigned int* __restrict__ abu) {
    __shared__ float rdeg[8];
    __shared__ int soff[9];
    __shared__ int sidx[FEDGE];
    int base = blockIdx.x * 8;
    int tid = threadIdx.x;
    if (tid < 9) soff[tid] = off[base + tid];
    if (tid < 8) rdeg[tid] = 1.0f / fmaxf((float)degi[base + tid], 1.0f);
    __syncthreads();
    int e0b = soff[0];
    int count = soff[8] - e0b;
    bool inl = (count <= FEDGE);  // uniform per block
    if (inl)
        for (int i = tid; i < count; i += 256) sidx[i] = csr[e0b + i];
    __syncthreads();

    int wave = tid >> 6, lane = tid & 63;
    int half = lane >> 5;       // node select within wave
    int grp = (lane >> 4) & 1;  // edge-slot within node
    int lg = lane & 15;         // covers bf16 cols 4*lg .. 4*lg+3
    int n = wave * 2 + half;
    int node = base + n;
    int e0 = soff[n], e1 = soff[n + 1];
    float a0 = 0, a1 = 0, a2 = 0, a3 = 0;
    float b0 = 0, b1 = 0, b2 = 0, b3 = 0;
    float c0 = 0, c1 = 0, c2 = 0, c3 = 0;
    float d0 = 0, d1 = 0, d2 = 0, d3 = 0;
    int e = e0;
    // main: 8 edges/iter -> 4 independent uint2 loads in flight per lane
    for (; e + 8 <= e1; e += 8) {
        int r0 = inl ? sidx[e + grp - e0b] : csr[e + grp];
        int r1 = inl ? sidx[e + 2 + grp - e0b] : csr[e + 2 + grp];
        int r2 = inl ? sidx[e + 4 + grp - e0b] : csr[e + 4 + grp];
        int r3 = inl ? sidx[e + 6 + grp - e0b] : csr[e + 6 + grp];
        uint2 u0 = xb2[(size_t)r0 * 16 + lg];
        uint2 u1 = xb2[(size_t)r1 * 16 + lg];
        uint2 u2 = xb2[(size_t)r2 * 16 + lg];
        uint2 u3 = xb2[(size_t)r3 * 16 + lg];
        a0 += uf(u0.x << 16);
        a1 += uf(u0.x & 0xffff0000u);
        a2 += uf(u0.y << 16);
        a3 += uf(u0.y & 0xffff0000u);
        b0 += uf(u1.x << 16);
        b1 += uf(u1.x & 0xffff0000u);
        b2 += uf(u1.y << 16);
        b3 += uf(u1.y & 0xffff0000u);
        c0 += uf(u2.x << 16);
        c1 += uf(u2.x & 0xffff0000u);
        c2 += uf(u2.y << 16);
        c3 += uf(u2.y & 0xffff0000u);
        d0 += uf(u3.x << 16);
        d1 += uf(u3.x & 0xffff0000u);
        d2 += uf(u3.y << 16);
        d3 += uf(u3.y & 0xffff0000u);
    }
    for (; e + 4 <= e1; e += 4) {
        int r0 = inl ? sidx[e + grp - e0b] : csr[e + grp];
        int r1 = inl ? sidx[e + 2 + grp - e0b] : csr[e + 2 + grp];
        uint2 u0 = xb2[(size_t)r0 * 16 + lg];
        uint2 u1 = xb2[(size_t)r1 * 16 + lg];
        a0 += uf(u0.x << 16);
        a1 += uf(u0.x & 0xffff0000u);
        a2 += uf(u0.y << 16);
        a3 += uf(u0.y & 0xffff0000u);
        b0 += uf(u1.x << 16);
        b1 += uf(u1.x & 0xffff0000u);
        b2 += uf(u1.y << 16);
        b3 += uf(u1.y & 0xffff0000u);
    }
    for (; e < e1; e += 2) {
        int idx = e + grp;
        int safe = idx < e1 ? idx : e;
        int r0 = inl ? sidx[safe - e0b] : csr[safe];
        uint2 u0 = xb2[(size_t)r0 * 16 + lg];
        if (idx < e1) {
            a0 += uf(u0.x << 16);
            a1 += uf(u0.x & 0xffff0000u);
            a2 += uf(u0.y << 16);
            a3 += uf(u0.y & 0xffff0000u);
        }
    }
    a0 += b0 + c0 + d0;
    a1 += b1 + c1 + d1;
    a2 += b2 + c2 + d2;
    a3 += b3 + c3 + d3;
    a0 += __shfl_xor(a0, 16, 64);
    a1 += __shfl_xor(a1, 16, 64);
    a2 += __shfl_xor(a2, 16, 64);
    a3 += __shfl_xor(a3, 16, 64);
    if (grp == 0) {
        float r = rdeg[n];
        bf16 v0 = __float2bfloat16(a0 * r), v1 = __float2bfloat16(a1 * r);
        bf16 v2 = __float2bfloat16(a2 * r), v3 = __float2bfloat16(a3 * r);
        unsigned p0 = (unsigned)*(unsigned short*)&v0 |
                      ((unsigned)*(unsigned short*)&v1 << 16);
        unsigned p1 = (unsigned)*(unsigned short*)&v2 |
                      ((unsigned)*(unsigned short*)&v3 << 16);
        abu[(size_t)node * 64 + 2 * lg] = p0;
        abu[(size_t)node * 64 + 2 * lg + 1] = p1;
    }
}

// ---------------- proj1 (MFMA): proven r17 structure + __expf ELU -----------
__global__ __launch_bounds__(256) void proj1_r27(
    const bf16* __restrict__ ab_, const bf16* __restrict__ bw1,
    const float* __restrict__ b1, const float* __restrict__ bl1,
    bf16* __restrict__ hb) {
    __shared__ float os[16][516];
    __shared__ float partial[16][17];
    __shared__ float rns[16];

    int base = blockIdx.x * 16;
    int tid = threadIdx.x;
    int wave = tid >> 6, lane = tid & 63;
    int rc = lane & 15, quad = lane >> 4;

    const short* ab = (const short*)ab_;
    short8 af[4];
#pragma unroll
    for (int kt = 0; kt < 4; ++kt)
        af[kt] = *(const short8*)&ab[(size_t)(base + rc) * 128 + kt * 32 + quad * 8];

    const short* bws = (const short*)bw1;
    for (int ti = 0; ti < 8; ++ti) {
        int t = wave * 8 + ti;
        f32x4 acc = {0.0f, 0.0f, 0.0f, 0.0f};
#pragma unroll
        for (int kt = 0; kt < 4; ++kt) {
            short8 bf = *(const short8*)
                &bws[(((size_t)kt * 512 + t * 16 + rc) * 4 + quad) * 8];
            acc = __builtin_amdgcn_mfma_f32_16x16x32_bf16(af[kt], bf, acc, 0, 0, 0);
        }
        int col = t * 16 + rc;
#pragma unroll
        for (int r = 0; r < 4; ++r) os[quad * 4 + r][col] = acc[r];
    }
    __syncthreads();
    {
        int n = tid & 15, jj = tid >> 4;
        float s = 0.0f;
#pragma unroll
        for (int c = 0; c < 16; ++c) {
            int cc = jj * 16 + c;
            float v = os[n][cc] + b1[cc];
            s += v * v;
        }
        partial[n][jj] = s;
    }
    __syncthreads();
    if (tid < 16) {
        float s = 0.0f;
#pragma unroll
        for (int jj = 0; jj < 16; ++jj) s += partial[tid][jj];
        rns[tid] = 1.0f / fmaxf(sqrtf(s), 1e-12f);
    }
    __syncthreads();
    for (int i = 0; i < 16; ++i) {
        int idx = i * 256 + tid;
        int n = idx >> 8, c = idx & 255;
        float z = (os[n][c] + b1[c]) * rns[n] + os[n][256 + c] + bl1[c];
        z = z > 0.0f ? z : (__expf(z) - 1.0f);
        hb[(size_t)(base + n) * HIDDEN + c] = __float2bfloat16(z);
    }
}

// ---------------- proj2 (MFMA): 64 rows/block, B-frag reuse x4 --------------
__global__ __launch_bounds__(256) void proj2_r27(
    const bf16* __restrict__ hb, const bf16* __restrict__ bw,
    bf16* __restrict__ pb, bf16* __restrict__ qrb, bf16* __restrict__ qlb) {
    __shared__ __align__(16) short hs[P2ROWS * LDSPITCH];

    int base = blockIdx.x * P2ROWS;
    int tid = threadIdx.x;
    const short* hbs = (const short*)hb;
#pragma unroll
    for (int i = 0; i < 8; ++i) {
        int f = tid + 256 * i;  // 0..2047 ; row = f/32, 16B-chunk = f%32
        int row = f >> 5, u4 = f & 31;
        *(uint4*)&hs[row * LDSPITCH + u4 * 8] =
            *(const uint4*)(hbs + (size_t)(base + row) * HIDDEN + u4 * 8);
    }
    __syncthreads();

    int wave = tid >> 6, lane = tid & 63;
    int rc = lane & 15, quad = lane >> 4;

    short8 af[4][8];
#pragma unroll
    for (int rg = 0; rg < 4; ++rg)
#pragma unroll
        for (int kt = 0; kt < 8; ++kt)
            af[rg][kt] = *(const short8*)
                &hs[(rg * 16 + rc) * LDSPITCH + kt * 32 + quad * 8];

    const short* bws = (const short*)bw;
    for (int ti = 0; ti < 6; ++ti) {
        int t = wave * 6 + ti;  // 24 col tiles across 4 waves
        f32x4 acc[4] = {{0, 0, 0, 0}, {0, 0, 0, 0}, {0, 0, 0, 0}, {0, 0, 0, 0}};
#pragma unroll
        for (int kt = 0; kt < 8; ++kt) {
            short8 bf = *(const short8*)
                &bws[(((size_t)kt * 384 + t * 16 + rc) * 4 + quad) * 8];
#pragma unroll
            for (int rg = 0; rg < 4; ++rg)
                acc[rg] = __builtin_amdgcn_mfma_f32_16x16x32_bf16(af[rg][kt], bf,
                                                                  acc[rg], 0, 0, 0);
        }
        int col = t * 16 + rc;
        int mat = col >> 7, cls = col & 127;
        bf16* dstp = (mat == 0) ? pb : ((mat == 1) ? qrb : qlb);
#pragma unroll
        for (int rg = 0; rg < 4; ++rg)
#pragma unroll
            for (int r = 0; r < 4; ++r) {
                int node = base + rg * 16 + quad * 4 + r;
                if (node < N_NODES)
                    dstp[(size_t)node * PSTR + cls] = __float2bfloat16(acc[rg][r]);
            }
    }
}

// ---------------- final: uint4 row gather, 4 loads in flight ----------------
__global__ __launch_bounds__(256) void final_r27(
    const bf16* __restrict__ pb, const bf16* __restrict__ qrb,
    const bf16* __restrict__ qlb, const int* __restrict__ off,
    const int* __restrict__ csr, const int* __restrict__ degi,
    const float* __restrict__ b2, const float* __restrict__ bl2,
    float* __restrict__ out) {
    __shared__ float mp[8][128];
    __shared__ float red[8][128];
    __shared__ float rdeg[8];
    __shared__ int soff[9];
    __shared__ int sidx[FEDGE];

    const uint4* pbu4 = (const uint4*)pb;  // row = 16 uint4 (256B)
    int base = blockIdx.x * 8;
    int tid = threadIdx.x;
    if (tid < 9) soff[tid] = off[base + tid];
    if (tid < 8) rdeg[tid] = 1.0f / fmaxf((float)degi[base + tid], 1.0f);
    __syncthreads();
    int e0b = soff[0];
    int count = soff[8] - e0b;
    bool inl = (count <= FEDGE);  // uniform per block
    if (inl)
        for (int i = tid; i < count; i += 256) sidx[i] = csr[e0b + i];
    __syncthreads();

    int wv = tid >> 6, lane = tid & 63;
    int g = lane >> 4, lg = lane & 15;  // 4 groups x 16 lanes
#pragma unroll
    for (int i = 0; i < 2; ++i) {
        int n = wv * 2 + i;
        int e0 = soff[n], e1 = soff[n + 1];
        float a[8] = {0, 0, 0, 0, 0, 0, 0, 0};
        float b[8] = {0, 0, 0, 0, 0, 0, 0, 0};
        float c[8] = {0, 0, 0, 0, 0, 0, 0, 0};
        float d[8] = {0, 0, 0, 0, 0, 0, 0, 0};
        int e = e0;
        // main: 16 edges/iter -> 4 independent uint4 loads in flight per lane
        for (; e + 16 <= e1; e += 16) {
            int r0 = inl ? sidx[e + g - e0b] : csr[e + g];
            int r1 = inl ? sidx[e + 4 + g - e0b] : csr[e + 4 + g];
            int r2 = inl ? sidx[e + 8 + g - e0b] : csr[e + 8 + g];
            int r3 = inl ? sidx[e + 12 + g - e0b] : csr[e + 12 + g];
            uint4 u0 = pbu4[(size_t)r0 * 16 + lg];
            uint4 u1 = pbu4[(size_t)r1 * 16 + lg];
            uint4 u2 = pbu4[(size_t)r2 * 16 + lg];
            uint4 u3 = pbu4[(size_t)r3 * 16 + lg];
            a[0] += uf(u0.x << 16);
            a[1] += uf(u0.x & 0xffff0000u);
            a[2] += uf(u0.y << 16);
            a[3] += uf(u0.y & 0xffff0000u);
            a[4] += uf(u0.z << 16);
            a[5] += uf(u0.z & 0xffff0000u);
            a[6] += uf(u0.w << 16);
            a[7] += uf(u0.w & 0xffff0000u);
            b[0] += uf(u1.x << 16);
            b[1] += uf(u1.x & 0xffff0000u);
            b[2] += uf(u1.y << 16);
            b[3] += uf(u1.y & 0xffff0000u);
            b[4] += uf(u1.z << 16);
            b[5] += uf(u1.z & 0xffff0000u);
            b[6] += uf(u1.w << 16);
            b[7] += uf(u1.w & 0xffff0000u);
            c[0] += uf(u2.x << 16);
            c[1] += uf(u2.x & 0xffff0000u);
            c[2] += uf(u2.y << 16);
            c[3] += uf(u2.y & 0xffff0000u);
            c[4] += uf(u2.z << 16);
            c[5] += uf(u2.z & 0xffff0000u);
            c[6] += uf(u2.w << 16);
            c[7] += uf(u2.w & 0xffff0000u);
            d[0] += uf(u3.x << 16);
            d[1] += uf(u3.x & 0xffff0000u);
            d[2] += uf(u3.y << 16);
            d[3] += uf(u3.y & 0xffff0000u);
            d[4] += uf(u3.z << 16);
            d[5] += uf(u3.z & 0xffff0000u);
            d[6] += uf(u3.w << 16);
            d[7] += uf(u3.w & 0xffff0000u);
        }
        for (; e + 8 <= e1; e += 8) {
            int r0 = inl ? sidx[e + g - e0b] : csr[e + g];
            int r1 = inl ? sidx[e + 4 + g - e0b] : csr[e + 4 + g];
            uint4 u0 = pbu4[(size_t)r0 * 16 + lg];
            uint4 u1 = pbu4[(size_t)r1 * 16 + lg];
            a[0] += uf(u0.x << 16);
            a[1] += uf(u0.x & 0xffff0000u);
            a[2] += uf(u0.y << 16);
            a[3] += uf(u0.y & 0xffff0000u);
            a[4] += uf(u0.z << 16);
            a[5] += uf(u0.z & 0xffff0000u);
            a[6] += uf(u0.w << 16);
            a[7] += uf(u0.w & 0xffff0000u);
            b[0] += uf(u1.x << 16);
            b[1] += uf(u1.x & 0xffff0000u);
            b[2] += uf(u1.y << 16);
            b[3] += uf(u1.y & 0xffff0000u);
            b[4] += uf(u1.z << 16);
            b[5] += uf(u1.z & 0xffff0000u);
            b[6] += uf(u1.w << 16);
            b[7] += uf(u1.w & 0xffff0000u);
        }
        for (; e < e1; e += 4) {
            int idx = e + g;
            int safe = idx < e1 ? idx : e;
            int r0 = inl ? sidx[safe - e0b] : csr[safe];
            uint4 u0 = pbu4[(size_t)r0 * 16 + lg];
            if (idx < e1) {
                a[0] += uf(u0.x << 16);
                a[1] += uf(u0.x & 0xffff0000u);
                a[2] += uf(u0.y << 16);
                a[3] += uf(u0.y & 0xffff0000u);
                a[4] += uf(u0.z << 16);
                a[5] += uf(u0.z & 0xffff0000u);
                a[6] += uf(u0.w << 16);
                a[7] += uf(u0.w & 0xffff0000u);
            }
        }
#pragma unroll
        for (int k = 0; k < 8; ++k) a[k] += (b[k] + c[k]) + d[k];
#pragma unroll
        for (int k = 0; k < 8; ++k) {
            a[k] += __shfl_xor(a[k], 16, 64);
            a[k] += __shfl_xor(a[k], 32, 64);
        }
        if (g == 0) {
#pragma unroll
            for (int k = 0; k < 8; ++k) mp[n][8 * lg + k] = a[k];
        }
    }
    __syncthreads();

    int j = tid & 127, gg = tid >> 7;
    float bj = (j < NCLS) ? b2[j] : 0.0f;
    float blj = (j < NCLS) ? bl2[j] : 0.0f;
    float out2[4];
#pragma unroll
    for (int i = 0; i < 4; ++i) {
        int n = gg * 4 + i;
        out2[i] = (j < NCLS)
                      ? (mp[n][j] * rdeg[n] + bj +
                         __bfloat162float(qrb[(size_t)(base + n) * PSTR + j]))
                      : 0.0f;
        red[n][j] = out2[i] * out2[i];
    }
    __syncthreads();
    for (int stride = 64; stride > 0; stride >>= 1) {
        if (j < stride) {
#pragma unroll
            for (int i = 0; i < 4; ++i)
                red[gg * 4 + i][j] += red[gg * 4 + i][j + stride];
        }
        __syncthreads();
    }
    if (j < NCLS) {
#pragma unroll
        for (int i = 0; i < 4; ++i) {
            int n = gg * 4 + i;
            float rn = 1.0f / fmaxf(sqrtf(red[n][0]), 1e-12f);
            out[(base + n) * NCLS + j] =
                out2[i] * rn +
                __bfloat162float(qlb[(size_t)(base + n) * PSTR + j]) + blj;
        }
    }
}

extern "C" void kernel_launch(void* const* d_in, const int* in_sizes, int n_in,
                              void* d_out, int out_size, void* d_ws, size_t ws_size,
                              hipStream_t stream) {
    const float* x   = (const float*)d_in[0];
    const int*   ei  = (const int*)d_in[1];
    const float* w1l = (const float*)d_in[2];
    const float* b1  = (const float*)d_in[3];
    const float* w1r = (const float*)d_in[4];
    const float* wl1 = (const float*)d_in[5];
    const float* bl1 = (const float*)d_in[6];
    const float* w2l = (const float*)d_in[7];
    const float* b2  = (const float*)d_in[8];
    const float* w2r = (const float*)d_in[9];
    const float* wl2 = (const float*)d_in[10];
    const float* bl2 = (const float*)d_in[11];
    float* out = (float*)d_out;

    const int* src = ei;
    const int* dst = ei + N_EDGES;

    int*   wsI   = (int*)d_ws;
    float* wsF   = (float*)d_ws;
    int*   degi  = wsI;
    int*   off   = wsI + OFF_OFF;
    int*   csr   = wsI + OFF_CSR;
    bf16*  hb    = (bf16*)(wsF + OFF_HB);
    int*   rank  = (int*)(wsF + OFF_HB);  // aliases hb; dead before proj1 writes hb
    bf16*  pb    = (bf16*)(wsF + OFF_PB);
    bf16*  xbp   = (bf16*)(wsF + OFF_PB); // aliases pb; dead before proj2 writes pb
    bf16*  ab    = (bf16*)(wsF + OFF_AB);
    bf16*  qrb   = (bf16*)(wsF + OFF_QRB);
    bf16*  qlb   = (bf16*)(wsF + OFF_QLB);
    bf16*  bw    = (bf16*)(wsF + OFF_BW);
    bf16*  bw1   = (bf16*)(wsF + OFF_BW1);
    int*   csum  = wsI + OFF_CSUM;

    prep_r27<<<25836, 256, 0, stream>>>(x, xbp, ab, w1l, w1r, wl1, bw1,
                                        w2l, w2r, wl2, bw, degi);

    degrank_r27<<<(N_EDGES + 255) / 256, 256, 0, stream>>>(dst, degi, rank);

    chunksum_r27<<<NCHUNK, 256, 0, stream>>>(degi, csum);
    scanscatter_r27<<<NCHUNK, 256, 0, stream>>>(csum, degi, off);

    csrfill2_r27<<<(N_EDGES + 255) / 256, 256, 0, stream>>>(src, dst, rank, off, csr);

    gather1_r27<<<N_NODES / 8, 256, 0, stream>>>((const uint2*)xbp, off,
                                                 csr, degi, (unsigned int*)ab);
    proj1_r27<<<N_NODES / 16, 256, 0, stream>>>(ab, bw1, b1, bl1, hb);
    proj2_r27<<<(N_NODES + P2ROWS - 1) / P2ROWS, 256, 0, stream>>>(hb, bw, pb, qrb, qlb);
    final_r27<<<N_NODES / 8, 256, 0, stream>>>(pb, qrb, qlb,
                                               off, csr, degi, b2, bl2, out);
}

// Round 11
// 278.482 us; speedup vs baseline: 1.0117x; 1.0117x over previous
//
#include <hip/hip_runtime.h>
#include <hip/hip_bf16.h>
#include <math.h>

typedef __hip_bfloat16 bf16;
typedef __attribute__((ext_vector_type(8))) short short8;
typedef __attribute__((ext_vector_type(4))) float f32x4;

#define N_NODES 50000
#define N_EDGES 800000
#define IN_DIM 50
#define HIDDEN 256
#define NCLS 121
#define PSTR 128     // padded stride for pb/qrb/qlb rows (bf16)
#define LDSPITCH 264 // proj2 LDS pitch (bf16)
#define NCHUNK 196   // ceil(50000/256) scan chunks
#define P2ROWS 64    // proj2 rows per block (B-fragment reuse x4)
#define FEDGE 1024   // LDS-staged csr indices per block (8 nodes, avg 128)

// ---- workspace layout (4-byte units) ----
// degi 0..50000 | off 50048.. | csr 150160..950160
// hb  bf16 50000x256 : [950272, 7350272)   -- ALSO aliased as rank[] (int, 800000)
// pb  bf16 50000x128 : [7350272, 10550272) -- ALSO aliased as xbp (bf16 50000x64)
// ab  bf16 50000x128 : [10550272, 13750272)
// qrb bf16 50000x128 : [15000272, 18200272)
// qlb bf16 50000x128 : [18200272, 21400272)
// bw  bf16 8*384*32  : [21400272, 21449424)
// bw1 bf16 4*512*32  : [21449424, 21482192)
// csum int [21482240,+196)
#define OFF_OFF   50048
#define OFF_CSR   150160
#define OFF_HB    950272
#define OFF_PB    7350272
#define OFF_AB    10550272
#define OFF_QRB   15000272
#define OFF_QLB   18200272
#define OFF_BW    21400272
#define OFF_BW1   21449424
#define OFF_CSUM  21482240

__device__ __forceinline__ int clampi(int v, int hi) {
    return v < 0 ? 0 : (v >= hi ? hi - 1 : v);
}

__device__ __forceinline__ float uf(unsigned u) { return __uint_as_float(u); }

// ---------------- prep: convx(+xbp) + packw1 + packw2 + degi zero -----------
__global__ __launch_bounds__(256) void prep_r28(
    const float* __restrict__ x, bf16* __restrict__ xbp, bf16* __restrict__ ab,
    const float* __restrict__ w1l, const float* __restrict__ w1r,
    const float* __restrict__ wl1, bf16* __restrict__ bw1,
    const float* __restrict__ w2l, const float* __restrict__ w2r,
    const float* __restrict__ wl2, bf16* __restrict__ bw,
    int* __restrict__ degi) {
    int b = blockIdx.x;
    if (b < 25000) {
        int i = b * 256 + threadIdx.x;  // < 6,400,000 exactly
        int n = i >> 7, c = i & 127;
        float v = 0.0f;
        if (c >= 64 && c < 64 + IN_DIM) v = x[n * IN_DIM + (c - 64)];
        ab[i] = __float2bfloat16(v);
        if (c < 64) {
            float xv = (c < IN_DIM) ? x[n * IN_DIM + c] : 0.0f;
            xbp[n * 64 + c] = __float2bfloat16(xv);
        }
    } else if (b < 25256) {
        int i = (b - 25000) * 256 + threadIdx.x;  // < 65536 exactly
        int kt = i / 16384, r = i % 16384, c = r / 32, t32 = r % 32;
        int q = t32 >> 3, j = t32 & 7;
        int k = kt * 32 + q * 8 + j;  // 0..127
        float v = 0.0f;
        if (k < 64) {
            if (k < IN_DIM && c < 256) v = w1l[k * HIDDEN + c];
        } else {
            int kr = k - 64;
            if (kr < IN_DIM)
                v = (c < 256) ? w1r[kr * HIDDEN + c] : wl1[kr * HIDDEN + (c - 256)];
        }
        bw1[i] = __float2bfloat16(v);
    } else if (b < 25640) {
        int i = (b - 25256) * 256 + threadIdx.x;  // < 98304 exactly
        int kt = i / 12288, r = i % 12288, c = r / 32, t32 = r % 32;
        int q = t32 >> 3, j = t32 & 7;
        int k = kt * 32 + q * 8 + j;
        int mat = c >> 7, cls = c & 127;
        float v = 0.0f;
        if (cls < NCLS) {
            const float* w = (mat == 0) ? w2l : ((mat == 1) ? w2r : wl2);
            v = w[k * NCLS + cls];
        }
        bw[i] = __float2bfloat16(v);
    } else {
        int i = (b - 25640) * 256 + threadIdx.x;
        if (i < N_NODES) degi[i] = 0;
    }
}

// ---------------- degrank: count degree AND record per-edge rank ------------
__global__ __launch_bounds__(256) void degrank_r28(const int* __restrict__ dst,
                                                   int* __restrict__ degi,
                                                   int* __restrict__ rank) {
    int e = blockIdx.x * 256 + threadIdx.x;
    if (e < N_EDGES) {
        int d = clampi(dst[e], N_NODES);
        rank[e] = atomicAdd(&degi[d], 1);
    }
}

// ---------------- scan phase 1: per-chunk sums ----------------
__global__ __launch_bounds__(256) void chunksum_r28(const int* __restrict__ degi,
                                                    int* __restrict__ csum) {
    __shared__ int red[256];
    int i = blockIdx.x * 256 + threadIdx.x;
    red[threadIdx.x] = (i < N_NODES) ? degi[i] : 0;
    __syncthreads();
    for (int s = 128; s > 0; s >>= 1) {
        if (threadIdx.x < s) red[threadIdx.x] += red[threadIdx.x + s];
        __syncthreads();
    }
    if (threadIdx.x == 0) csum[blockIdx.x] = red[0];
}

// ---------------- scan phase 2 (merged): chunk scan + per-chunk scatter -----
__global__ __launch_bounds__(256) void scanscatter_r28(const int* __restrict__ csum,
                                                       const int* __restrict__ degi,
                                                       int* __restrict__ off) {
    __shared__ int cs[256];
    __shared__ int s[256];
    int t = threadIdx.x;
    int cv = (t < NCHUNK) ? csum[t] : 0;
    cs[t] = cv;
    __syncthreads();
    for (int d = 1; d < 256; d <<= 1) {
        int u = (t >= d) ? cs[t - d] : 0;
        __syncthreads();
        cs[t] += u;
        __syncthreads();
    }
    int cb = cs[blockIdx.x] - csum[blockIdx.x];  // exclusive base of this chunk
    if (blockIdx.x == 0 && t == 0) off[N_NODES] = cs[NCHUNK - 1];
    int i = blockIdx.x * 256 + t;
    int dv = (i < N_NODES) ? degi[i] : 0;
    s[t] = dv;
    __syncthreads();
    for (int d = 1; d < 256; d <<= 1) {
        int u = (t >= d) ? s[t - d] : 0;
        __syncthreads();
        s[t] += u;
        __syncthreads();
    }
    if (i < N_NODES) off[i] = s[t] - dv + cb;
}

// ---------------- csrfill2: atomic-free scatter using precomputed ranks -----
__global__ __launch_bounds__(256) void csrfill2_r28(const int* __restrict__ src,
                                                    const int* __restrict__ dst,
                                                    const int* __restrict__ rank,
                                                    const int* __restrict__ off,
                                                    int* __restrict__ csr) {
    int e = blockIdx.x * 256 + threadIdx.x;
    if (e >= N_EDGES) return;
    int d = clampi(dst[e], N_NODES);
    csr[off[d] + rank[e]] = clampi(src[e], N_NODES);
}

// ---------------- gather1: mean-aggregate x, LDS-staged indices -------------
__global__ __launch_bounds__(256) void gather1_r28(
    const uint2* __restrict__ xb2, const int* __restrict__ off,
    const int* __restrict__ csr, const int* __restrict__ degi,
    unsigned int* __restrict__ abu) {
    __shared__ float rdeg[8];
    __shared__ int soff[9];
    __shared__ int sidx[FEDGE];
    int base = blockIdx.x * 8;
    int tid = threadIdx.x;
    if (tid < 9) soff[tid] = off[base + tid];
    if (tid < 8) rdeg[tid] = 1.0f / fmaxf((float)degi[base + tid], 1.0f);
    __syncthreads();
    int e0b = soff[0];
    int count = soff[8] - e0b;
    bool inl = (count <= FEDGE);  // uniform per block
    if (inl)
        for (int i = tid; i < count; i += 256) sidx[i] = csr[e0b + i];
    __syncthreads();

    int wave = tid >> 6, lane = tid & 63;
    int half = lane >> 5;       // node select within wave
    int grp = (lane >> 4) & 1;  // edge-slot within node
    int lg = lane & 15;         // covers bf16 cols 4*lg .. 4*lg+3
    int n = wave * 2 + half;
    int node = base + n;
    int e0 = soff[n], e1 = soff[n + 1];
    float a0 = 0, a1 = 0, a2 = 0, a3 = 0;
    float b0 = 0, b1 = 0, b2 = 0, b3 = 0;
    int e = e0;
    for (; e + 4 <= e1; e += 4) {
        int r0 = inl ? sidx[e + grp - e0b] : csr[e + grp];
        int r1 = inl ? sidx[e + 2 + grp - e0b] : csr[e + 2 + grp];
        uint2 u0 = xb2[(size_t)r0 * 16 + lg];
        uint2 u1 = xb2[(size_t)r1 * 16 + lg];
        a0 += uf(u0.x << 16);
        a1 += uf(u0.x & 0xffff0000u);
        a2 += uf(u0.y << 16);
        a3 += uf(u0.y & 0xffff0000u);
        b0 += uf(u1.x << 16);
        b1 += uf(u1.x & 0xffff0000u);
        b2 += uf(u1.y << 16);
        b3 += uf(u1.y & 0xffff0000u);
    }
    for (; e < e1; e += 2) {
        int idx = e + grp;
        int safe = idx < e1 ? idx : e;
        int r0 = inl ? sidx[safe - e0b] : csr[safe];
        uint2 u0 = xb2[(size_t)r0 * 16 + lg];
        if (idx < e1) {
            a0 += uf(u0.x << 16);
            a1 += uf(u0.x & 0xffff0000u);
            a2 += uf(u0.y << 16);
            a3 += uf(u0.y & 0xffff0000u);
        }
    }
    a0 += b0;
    a1 += b1;
    a2 += b2;
    a3 += b3;
    a0 += __shfl_xor(a0, 16, 64);
    a1 += __shfl_xor(a1, 16, 64);
    a2 += __shfl_xor(a2, 16, 64);
    a3 += __shfl_xor(a3, 16, 64);
    if (grp == 0) {
        float r = rdeg[n];
        bf16 v0 = __float2bfloat16(a0 * r), v1 = __float2bfloat16(a1 * r);
        bf16 v2 = __float2bfloat16(a2 * r), v3 = __float2bfloat16(a3 * r);
        unsigned p0 = (unsigned)*(unsigned short*)&v0 |
                      ((unsigned)*(unsigned short*)&v1 << 16);
        unsigned p1 = (unsigned)*(unsigned short*)&v2 |
                      ((unsigned)*(unsigned short*)&v3 << 16);
        abu[(size_t)node * 64 + 2 * lg] = p0;
        abu[(size_t)node * 64 + 2 * lg + 1] = p1;
    }
}

// ---------------- proj1 (MFMA): proven r17 structure + __expf ELU -----------
__global__ __launch_bounds__(256) void proj1_r28(
    const bf16* __restrict__ ab_, const bf16* __restrict__ bw1,
    const float* __restrict__ b1, const float* __restrict__ bl1,
    bf16* __restrict__ hb) {
    __shared__ float os[16][516];
    __shared__ float partial[16][17];
    __shared__ float rns[16];

    int base = blockIdx.x * 16;
    int tid = threadIdx.x;
    int wave = tid >> 6, lane = tid & 63;
    int rc = lane & 15, quad = lane >> 4;

    const short* ab = (const short*)ab_;
    short8 af[4];
#pragma unroll
    for (int kt = 0; kt < 4; ++kt)
        af[kt] = *(const short8*)&ab[(size_t)(base + rc) * 128 + kt * 32 + quad * 8];

    const short* bws = (const short*)bw1;
    for (int ti = 0; ti < 8; ++ti) {
        int t = wave * 8 + ti;
        f32x4 acc = {0.0f, 0.0f, 0.0f, 0.0f};
#pragma unroll
        for (int kt = 0; kt < 4; ++kt) {
            short8 bf = *(const short8*)
                &bws[(((size_t)kt * 512 + t * 16 + rc) * 4 + quad) * 8];
            acc = __builtin_amdgcn_mfma_f32_16x16x32_bf16(af[kt], bf, acc, 0, 0, 0);
        }
        int col = t * 16 + rc;
#pragma unroll
        for (int r = 0; r < 4; ++r) os[quad * 4 + r][col] = acc[r];
    }
    __syncthreads();
    {
        int n = tid & 15, jj = tid >> 4;
        float s = 0.0f;
#pragma unroll
        for (int c = 0; c < 16; ++c) {
            int cc = jj * 16 + c;
            float v = os[n][cc] + b1[cc];
            s += v * v;
        }
        partial[n][jj] = s;
    }
    __syncthreads();
    if (tid < 16) {
        float s = 0.0f;
#pragma unroll
        for (int jj = 0; jj < 16; ++jj) s += partial[tid][jj];
        rns[tid] = 1.0f / fmaxf(sqrtf(s), 1e-12f);
    }
    __syncthreads();
    for (int i = 0; i < 16; ++i) {
        int idx = i * 256 + tid;
        int n = idx >> 8, c = idx & 255;
        float z = (os[n][c] + b1[c]) * rns[n] + os[n][256 + c] + bl1[c];
        z = z > 0.0f ? z : (__expf(z) - 1.0f);
        hb[(size_t)(base + n) * HIDDEN + c] = __float2bfloat16(z);
    }
}

// ---------------- proj2 (MFMA): 64 rows/block, B-frag reuse x4 --------------
__global__ __launch_bounds__(256) void proj2_r28(
    const bf16* __restrict__ hb, const bf16* __restrict__ bw,
    bf16* __restrict__ pb, bf16* __restrict__ qrb, bf16* __restrict__ qlb) {
    __shared__ __align__(16) short hs[P2ROWS * LDSPITCH];

    int base = blockIdx.x * P2ROWS;
    int tid = threadIdx.x;
    const short* hbs = (const short*)hb;
#pragma unroll
    for (int i = 0; i < 8; ++i) {
        int f = tid + 256 * i;  // 0..2047 ; row = f/32, 16B-chunk = f%32
        int row = f >> 5, u4 = f & 31;
        *(uint4*)&hs[row * LDSPITCH + u4 * 8] =
            *(const uint4*)(hbs + (size_t)(base + row) * HIDDEN + u4 * 8);
    }
    __syncthreads();

    int wave = tid >> 6, lane = tid & 63;
    int rc = lane & 15, quad = lane >> 4;

    short8 af[4][8];
#pragma unroll
    for (int rg = 0; rg < 4; ++rg)
#pragma unroll
        for (int kt = 0; kt < 8; ++kt)
            af[rg][kt] = *(const short8*)
                &hs[(rg * 16 + rc) * LDSPITCH + kt * 32 + quad * 8];

    const short* bws = (const short*)bw;
    for (int ti = 0; ti < 6; ++ti) {
        int t = wave * 6 + ti;  // 24 col tiles across 4 waves
        f32x4 acc[4] = {{0, 0, 0, 0}, {0, 0, 0, 0}, {0, 0, 0, 0}, {0, 0, 0, 0}};
#pragma unroll
        for (int kt = 0; kt < 8; ++kt) {
            short8 bf = *(const short8*)
                &bws[(((size_t)kt * 384 + t * 16 + rc) * 4 + quad) * 8];
#pragma unroll
            for (int rg = 0; rg < 4; ++rg)
                acc[rg] = __builtin_amdgcn_mfma_f32_16x16x32_bf16(af[rg][kt], bf,
                                                                  acc[rg], 0, 0, 0);
        }
        int col = t * 16 + rc;
        int mat = col >> 7, cls = col & 127;
        bf16* dstp = (mat == 0) ? pb : ((mat == 1) ? qrb : qlb);
#pragma unroll
        for (int rg = 0; rg < 4; ++rg)
#pragma unroll
            for (int r = 0; r < 4; ++r) {
                int node = base + rg * 16 + quad * 4 + r;
                if (node < N_NODES)
                    dstp[(size_t)node * PSTR + cls] = __float2bfloat16(acc[rg][r]);
            }
    }
}

// ---------------- final: uint4 row gather, LDS-staged indices ---------------
__global__ __launch_bounds__(256) void final_r28(
    const bf16* __restrict__ pb, const bf16* __restrict__ qrb,
    const bf16* __restrict__ qlb, const int* __restrict__ off,
    const int* __restrict__ csr, const int* __restrict__ degi,
    const float* __restrict__ b2, const float* __restrict__ bl2,
    float* __restrict__ out) {
    __shared__ float mp[8][128];
    __shared__ float red[8][128];
    __shared__ float rdeg[8];
    __shared__ int soff[9];
    __shared__ int sidx[FEDGE];

    const uint4* pbu4 = (const uint4*)pb;  // row = 16 uint4 (256B)
    int base = blockIdx.x * 8;
    int tid = threadIdx.x;
    if (tid < 9) soff[tid] = off[base + tid];
    if (tid < 8) rdeg[tid] = 1.0f / fmaxf((float)degi[base + tid], 1.0f);
    __syncthreads();
    int e0b = soff[0];
    int count = soff[8] - e0b;
    bool inl = (count <= FEDGE);  // uniform per block
    if (inl)
        for (int i = tid; i < count; i += 256) sidx[i] = csr[e0b + i];
    __syncthreads();

    int wv = tid >> 6, lane = tid & 63;
    int g = lane >> 4, lg = lane & 15;  // 4 groups x 16 lanes
#pragma unroll
    for (int i = 0; i < 2; ++i) {
        int n = wv * 2 + i;
        int e0 = soff[n], e1 = soff[n + 1];
        float a[8] = {0, 0, 0, 0, 0, 0, 0, 0};
        float b[8] = {0, 0, 0, 0, 0, 0, 0, 0};
        int e = e0;
        for (; e + 8 <= e1; e += 8) {
            int r0 = inl ? sidx[e + g - e0b] : csr[e + g];
            int r1 = inl ? sidx[e + 4 + g - e0b] : csr[e + 4 + g];
            uint4 u0 = pbu4[(size_t)r0 * 16 + lg];
            uint4 u1 = pbu4[(size_t)r1 * 16 + lg];
            a[0] += uf(u0.x << 16);
            a[1] += uf(u0.x & 0xffff0000u);
            a[2] += uf(u0.y << 16);
            a[3] += uf(u0.y & 0xffff0000u);
            a[4] += uf(u0.z << 16);
            a[5] += uf(u0.z & 0xffff0000u);
            a[6] += uf(u0.w << 16);
            a[7] += uf(u0.w & 0xffff0000u);
            b[0] += uf(u1.x << 16);
            b[1] += uf(u1.x & 0xffff0000u);
            b[2] += uf(u1.y << 16);
            b[3] += uf(u1.y & 0xffff0000u);
            b[4] += uf(u1.z << 16);
            b[5] += uf(u1.z & 0xffff0000u);
            b[6] += uf(u1.w << 16);
            b[7] += uf(u1.w & 0xffff0000u);
        }
        for (; e < e1; e += 4) {
            int idx = e + g;
            int safe = idx < e1 ? idx : e;
            int r0 = inl ? sidx[safe - e0b] : csr[safe];
            uint4 u0 = pbu4[(size_t)r0 * 16 + lg];
            if (idx < e1) {
                a[0] += uf(u0.x << 16);
                a[1] += uf(u0.x & 0xffff0000u);
                a[2] += uf(u0.y << 16);
                a[3] += uf(u0.y & 0xffff0000u);
                a[4] += uf(u0.z << 16);
                a[5] += uf(u0.z & 0xffff0000u);
                a[6] += uf(u0.w << 16);
                a[7] += uf(u0.w & 0xffff0000u);
            }
        }
#pragma unroll
        for (int k = 0; k < 8; ++k) a[k] += b[k];
#pragma unroll
        for (int k = 0; k < 8; ++k) {
            a[k] += __shfl_xor(a[k], 16, 64);
            a[k] += __shfl_xor(a[k], 32, 64);
        }
        if (g == 0) {
#pragma unroll
            for (int k = 0; k < 8; ++k) mp[n][8 * lg + k] = a[k];
        }
    }
    __syncthreads();

    int j = tid & 127, gg = tid >> 7;
    float bj = (j < NCLS) ? b2[j] : 0.0f;
    float blj = (j < NCLS) ? bl2[j] : 0.0f;
    float out2[4];
#pragma unroll
    for (int i = 0; i < 4; ++i) {
        int n = gg * 4 + i;
        out2[i] = (j < NCLS)
                      ? (mp[n][j] * rdeg[n] + bj +
                         __bfloat162float(qrb[(size_t)(base + n) * PSTR + j]))
                      : 0.0f;
        red[n][j] = out2[i] * out2[i];
    }
    __syncthreads();
    for (int stride = 64; stride > 0; stride >>= 1) {
        if (j < stride) {
#pragma unroll
            for (int i = 0; i < 4; ++i)
                red[gg * 4 + i][j] += red[gg * 4 + i][j + stride];
        }
        __syncthreads();
    }
    if (j < NCLS) {
#pragma unroll
        for (int i = 0; i < 4; ++i) {
            int n = gg * 4 + i;
            float rn = 1.0f / fmaxf(sqrtf(red[n][0]), 1e-12f);
            out[(base + n) * NCLS + j] =
                out2[i] * rn +
                __bfloat162float(qlb[(size_t)(base + n) * PSTR + j]) + blj;
        }
    }
}

extern "C" void kernel_launch(void* const* d_in, const int* in_sizes, int n_in,
                              void* d_out, int out_size, void* d_ws, size_t ws_size,
                              hipStream_t stream) {
    const float* x   = (const float*)d_in[0];
    const int*   ei  = (const int*)d_in[1];
    const float* w1l = (const float*)d_in[2];
    const float* b1  = (const float*)d_in[3];
    const float* w1r = (const float*)d_in[4];
    const float* wl1 = (const float*)d_in[5];
    const float* bl1 = (const float*)d_in[6];
    const float* w2l = (const float*)d_in[7];
    const float* b2  = (const float*)d_in[8];
    const float* w2r = (const float*)d_in[9];
    const float* wl2 = (const float*)d_in[10];
    const float* bl2 = (const float*)d_in[11];
    float* out = (float*)d_out;

    const int* src = ei;
    const int* dst = ei + N_EDGES;

    int*   wsI   = (int*)d_ws;
    float* wsF   = (float*)d_ws;
    int*   degi  = wsI;
    int*   off   = wsI + OFF_OFF;
    int*   csr   = wsI + OFF_CSR;
    bf16*  hb    = (bf16*)(wsF + OFF_HB);
    int*   rank  = (int*)(wsF + OFF_HB);  // aliases hb; dead before proj1 writes hb
    bf16*  pb    = (bf16*)(wsF + OFF_PB);
    bf16*  xbp   = (bf16*)(wsF + OFF_PB); // aliases pb; dead before proj2 writes pb
    bf16*  ab    = (bf16*)(wsF + OFF_AB);
    bf16*  qrb   = (bf16*)(wsF + OFF_QRB);
    bf16*  qlb   = (bf16*)(wsF + OFF_QLB);
    bf16*  bw    = (bf16*)(wsF + OFF_BW);
    bf16*  bw1   = (bf16*)(wsF + OFF_BW1);
    int*   csum  = wsI + OFF_CSUM;

    prep_r28<<<25836, 256, 0, stream>>>(x, xbp, ab, w1l, w1r, wl1, bw1,
                                        w2l, w2r, wl2, bw, degi);

    degrank_r28<<<(N_EDGES + 255) / 256, 256, 0, stream>>>(dst, degi, rank);

    chunksum_r28<<<NCHUNK, 256, 0, stream>>>(degi, csum);
    scanscatter_r28<<<NCHUNK, 256, 0, stream>>>(csum, degi, off);

    csrfill2_r28<<<(N_EDGES + 255) / 256, 256, 0, stream>>>(src, dst, rank, off, csr);

    gather1_r28<<<N_NODES / 8, 256, 0, stream>>>((const uint2*)xbp, off,
                                                 csr, degi, (unsigned int*)ab);
    proj1_r28<<<N_NODES / 16, 256, 0, stream>>>(ab, bw1, b1, bl1, hb);
    proj2_r28<<<(N_NODES + P2ROWS - 1) / P2ROWS, 256, 0, stream>>>(hb, bw, pb, qrb, qlb);
    final_r28<<<N_NODES / 8, 256, 0, stream>>>(pb, qrb, qlb,
                                               off, csr, degi, b2, bl2, out);
}